// Round 5
// baseline (277.220 us; speedup 1.0000x reference)
//
#include <hip/hip_runtime.h>
#include <stdint.h>

#define D_MODEL 2048
#define SEQ     2048
#define BATCH   2
#define NH      16
#define HD      128
#define M_TOT   (BATCH*SEQ)          // 4096
#define NELEM_W (D_MODEL*D_MODEL)    // 4194304

typedef float f32x4 __attribute__((ext_vector_type(4)));
typedef short bf16x8 __attribute__((ext_vector_type(8)));

__device__ __forceinline__ unsigned short f2bf(float f) {
  union { float f; uint32_t u; } v; v.f = f;
  uint32_t r = v.u + 0x7FFFu + ((v.u >> 16) & 1u);
  return (unsigned short)(r >> 16);
}

__device__ __forceinline__ void gload_lds16(const unsigned short* g, unsigned short* l) {
  __builtin_amdgcn_global_load_lds(
      (const __attribute__((address_space(1))) unsigned int*)g,
      (__attribute__((address_space(3))) unsigned int*)l, 16, 0, 0);
}

// ---------------- sign(w) as bf16 ±1, fused |w| partial reduction ----------------
__global__ __launch_bounds__(256) void sign_w(const float* w0, const float* w1,
                                              const float* w2, const float* w3,
                                              unsigned short* signs, float* partials) {
  const int wi = blockIdx.y;
  const float* w = (wi == 0) ? w0 : (wi == 1) ? w1 : (wi == 2) ? w2 : w3;
  unsigned short* o = signs + (size_t)wi * NELEM_W;
  const int t = threadIdx.x;
  const int i = blockIdx.x * 256 + t;
  float4 v = ((const float4*)w)[i];
  ushort4 s;
  s.x = (v.x > 0.f) ? 0x3F80u : ((v.x < 0.f) ? 0xBF80u : 0u);
  s.y = (v.y > 0.f) ? 0x3F80u : ((v.y < 0.f) ? 0xBF80u : 0u);
  s.z = (v.z > 0.f) ? 0x3F80u : ((v.z < 0.f) ? 0xBF80u : 0u);
  s.w = (v.w > 0.f) ? 0x3F80u : ((v.w < 0.f) ? 0xBF80u : 0u);
  ((ushort4*)o)[i] = s;
  float a = fabsf(v.x) + fabsf(v.y) + fabsf(v.z) + fabsf(v.w);
  #pragma unroll
  for (int off = 32; off; off >>= 1) a += __shfl_down(a, off);
  __shared__ float sm[4];
  if ((t & 63) == 0) sm[t >> 6] = a;
  __syncthreads();
  if (t == 0) partials[wi * 4096 + blockIdx.x] = sm[0] + sm[1] + sm[2] + sm[3];
}

__global__ __launch_bounds__(256) void reduce2(const float* partials, float* scales) {
  const int wi = blockIdx.x, t = threadIdx.x;
  float s = 0.f;
  #pragma unroll
  for (int i = 0; i < 16; ++i) s += partials[wi * 4096 + i * 256 + t];
  #pragma unroll
  for (int off = 32; off; off >>= 1) s += __shfl_down(s, off);
  __shared__ float sm[4];
  if ((t & 63) == 0) sm[t >> 6] = s;
  __syncthreads();
  if (t == 0) scales[wi] = fmaxf((sm[0] + sm[1] + sm[2] + sm[3]) * (1.f / 4194304.f), 1e-5f);
}

// ---------------- x -> bf16 ----------------
__global__ __launch_bounds__(256) void cvt_x(const float* x, unsigned short* xb) {
  const int i = blockIdx.x * 256 + threadIdx.x;
  float4 v = ((const float4*)x)[i];
  ushort4 o;
  o.x = f2bf(v.x); o.y = f2bf(v.y); o.z = f2bf(v.z); o.w = f2bf(v.w);
  ((ushort4*)xb)[i] = o;
}

// ---------------- pipelined GEMM: C[4096][NW*2048] = A[M][2048] * W[col][2048]^T ----
// BM=256, BN=128, BK=64, 8 waves, 3-buffer LDS, counted vmcnt(6), 4 phases/K-tile.
// MODE 0: fused QKV (W = signs base, 3 regions of 2048 cols -> Qb/Kb layout or Vt^T)
// MODE 1: f32 out row-major (WO)
template <int MODE>
__global__ __launch_bounds__(512, 2) void gemm_p(const unsigned short* __restrict__ A,
                                                 const unsigned short* __restrict__ W,
                                                 unsigned short* __restrict__ Qb,
                                                 unsigned short* __restrict__ Kb,
                                                 unsigned short* __restrict__ Vt,
                                                 float* __restrict__ outf,
                                                 const float* __restrict__ scales) {
  constexpr int K = 2048;
  constexpr int NT = K / 64;           // 32 K-tiles
  constexpr int BUF = 24576;           // 48 KB per buffer (A 32 KB + B 16 KB), elems
  __shared__ alignas(16) unsigned short lds[3 * BUF];   // 144 KB
  const int t = threadIdx.x;
  const int wid = t >> 6, lane = t & 63;
  const int llo = lane & 15, lhi = lane >> 4;
  const int wm = wid >> 1, wn = wid & 1;

  // XCD-aware swizzle (grid % 8 == 0), m-fast within XCD chunk (shares B panel)
  const int nwg = gridDim.x;
  const int bid = blockIdx.x;
  const int sid = (bid & 7) * (nwg >> 3) + (bid >> 3);
  const int mt = sid & 15, nt_ = sid >> 4;
  const int m0 = mt * 256;
  const int n0w = nt_ * 128;            // global weight-row (output col) base

  auto stageA = [&](int buf, int kt, int half) {
    const int k0 = kt * 64;
    #pragma unroll
    for (int i = half * 2; i < half * 2 + 2; ++i) {
      const int c = i * 512 + t;
      const int row = c >> 3, slot = c & 7;
      gload_lds16(A + (size_t)(m0 + row) * K + k0 + ((slot ^ (row & 7)) << 3),
                  &lds[buf * BUF + (i * 512 + wid * 64) * 8]);
    }
  };
  auto stageB = [&](int buf, int kt) {
    const int k0 = kt * 64;
    #pragma unroll
    for (int i = 0; i < 2; ++i) {
      const int c = i * 512 + t;
      const int row = c >> 3, slot = c & 7;
      gload_lds16(W + (size_t)(n0w + row) * K + k0 + ((slot ^ (row & 7)) << 3),
                  &lds[buf * BUF + 16384 + (i * 512 + wid * 64) * 8]);
    }
  };

  f32x4 acc[4][4] = {};
  bf16x8 a[2][2], b0[2][2], b1[2][2];

  auto rdA = [&](int cur, int mh) {
    #pragma unroll
    for (int fm = 0; fm < 2; ++fm) {
      const int ra = wm * 64 + mh * 32 + fm * 16 + llo;
      #pragma unroll
      for (int kk = 0; kk < 2; ++kk)
        a[fm][kk] = *(const bf16x8*)&lds[cur * BUF + ra * 64 + (((kk * 4 + lhi) ^ (ra & 7)) << 3)];
    }
  };

  stageA(0, 0, 0); stageA(0, 0, 1); stageB(0, 0);   // tile 0 -> buf 0 (6 loads)
  stageA(1, 1, 0); stageA(1, 1, 1); stageB(1, 1);   // tile 1 -> buf 1 (6 loads)
  asm volatile("s_waitcnt vmcnt(6)" ::: "memory");  // tile 0 landed
  __builtin_amdgcn_s_barrier();

  for (int kt = 0; kt < NT; ++kt) {
    const int cur = kt % 3;
    const int nb3 = (kt + 2) % 3;
    const bool pf = (kt + 2) < NT;
    // ---- phase 0: quad(0,0); prefetch A half 0 ----
    rdA(cur, 0);
    #pragma unroll
    for (int fn = 0; fn < 2; ++fn) {
      const int rb = wn * 64 + fn * 16 + llo;
      #pragma unroll
      for (int kk = 0; kk < 2; ++kk)
        b0[fn][kk] = *(const bf16x8*)&lds[cur * BUF + 16384 + rb * 64 + (((kk * 4 + lhi) ^ (rb & 7)) << 3)];
    }
    if (pf) stageA(nb3, kt + 2, 0);
    __builtin_amdgcn_s_barrier();
    asm volatile("s_waitcnt lgkmcnt(0)" ::: "memory");
    __builtin_amdgcn_sched_barrier(0);
    __builtin_amdgcn_s_setprio(1);
    #pragma unroll
    for (int kk = 0; kk < 2; ++kk)
      #pragma unroll
      for (int fm = 0; fm < 2; ++fm)
        #pragma unroll
        for (int fn = 0; fn < 2; ++fn)
          acc[fm][fn] = __builtin_amdgcn_mfma_f32_16x16x32_bf16(a[fm][kk], b0[fn][kk], acc[fm][fn], 0, 0, 0);
    __builtin_amdgcn_s_setprio(0);
    __builtin_amdgcn_s_barrier();
    // ---- phase 1: quad(0,1); prefetch A half 1 ----
    #pragma unroll
    for (int fn = 0; fn < 2; ++fn) {
      const int rb = wn * 64 + 32 + fn * 16 + llo;
      #pragma unroll
      for (int kk = 0; kk < 2; ++kk)
        b1[fn][kk] = *(const bf16x8*)&lds[cur * BUF + 16384 + rb * 64 + (((kk * 4 + lhi) ^ (rb & 7)) << 3)];
    }
    if (pf) stageA(nb3, kt + 2, 1);
    __builtin_amdgcn_s_barrier();
    asm volatile("s_waitcnt lgkmcnt(0)" ::: "memory");
    __builtin_amdgcn_sched_barrier(0);
    __builtin_amdgcn_s_setprio(1);
    #pragma unroll
    for (int kk = 0; kk < 2; ++kk)
      #pragma unroll
      for (int fm = 0; fm < 2; ++fm)
        #pragma unroll
        for (int fn = 0; fn < 2; ++fn)
          acc[fm][2 + fn] = __builtin_amdgcn_mfma_f32_16x16x32_bf16(a[fm][kk], b1[fn][kk], acc[fm][2 + fn], 0, 0, 0);
    __builtin_amdgcn_s_setprio(0);
    __builtin_amdgcn_s_barrier();
    // ---- phase 2: quad(1,1); prefetch B ----
    rdA(cur, 1);
    if (pf) stageB(nb3, kt + 2);
    __builtin_amdgcn_s_barrier();
    asm volatile("s_waitcnt lgkmcnt(0)" ::: "memory");
    __builtin_amdgcn_sched_barrier(0);
    __builtin_amdgcn_s_setprio(1);
    #pragma unroll
    for (int kk = 0; kk < 2; ++kk)
      #pragma unroll
      for (int fm = 0; fm < 2; ++fm)
        #pragma unroll
        for (int fn = 0; fn < 2; ++fn)
          acc[2 + fm][2 + fn] = __builtin_amdgcn_mfma_f32_16x16x32_bf16(a[fm][kk], b1[fn][kk], acc[2 + fm][2 + fn], 0, 0, 0);
    __builtin_amdgcn_s_setprio(0);
    __builtin_amdgcn_s_barrier();
    // ---- phase 3: quad(1,0); counted vmcnt (next tile landed; tile+2 in flight) ----
    if (pf) asm volatile("s_waitcnt vmcnt(6)" ::: "memory");
    else    asm volatile("s_waitcnt vmcnt(0)" ::: "memory");
    __builtin_amdgcn_s_barrier();
    __builtin_amdgcn_s_setprio(1);
    #pragma unroll
    for (int kk = 0; kk < 2; ++kk)
      #pragma unroll
      for (int fm = 0; fm < 2; ++fm)
        #pragma unroll
        for (int fn = 0; fn < 2; ++fn)
          acc[2 + fm][fn] = __builtin_amdgcn_mfma_f32_16x16x32_bf16(a[fm][kk], b0[fn][kk], acc[2 + fm][fn], 0, 0, 0);
    __builtin_amdgcn_s_setprio(0);
    __builtin_amdgcn_s_barrier();
  }

  // ---- epilogue ----
  if (MODE == 1) {
    const float sc = scales[3];
    #pragma unroll
    for (int fm = 0; fm < 4; ++fm)
      #pragma unroll
      for (int fn = 0; fn < 4; ++fn)
        #pragma unroll
        for (int r = 0; r < 4; ++r) {
          const int row = m0 + wm * 64 + fm * 16 + lhi * 4 + r;
          const int col = n0w + wn * 64 + fn * 16 + llo;
          outf[(size_t)row * D_MODEL + col] = acc[fm][fn][r] * sc;
        }
  } else {
    const int region = n0w >> 11;                 // 0=Q 1=K 2=V
    const int c0 = (n0w & 2047) + wn * 64;        // col base within region
    const float sc = scales[region] * (region == 0 ? 0.08838834764831845f : 1.f);
    unsigned short* outb = (region == 0) ? Qb : (region == 1) ? Kb : Vt;
    #pragma unroll
    for (int fm = 0; fm < 4; ++fm)
      #pragma unroll
      for (int fn = 0; fn < 4; ++fn)
        #pragma unroll
        for (int r = 0; r < 4; ++r) {
          const int row = m0 + wm * 64 + fm * 16 + lhi * 4 + r;
          const int colr = c0 + fn * 16 + llo;
          const int b = row >> 11, tt = row & 2047, h = colr >> 7, d = colr & 127;
          size_t idx;
          if (region < 2) idx = ((size_t)((b * NH + h) * SEQ + tt)) * HD + d;
          else            idx = ((size_t)((b * NH + h) * HD + d)) * SEQ + tt;
          outb[idx] = f2bf(acc[fm][fn][r] * sc);
        }
  }
}

// ---------------- causal flash attention (8-wave, QBLK=128, swapped QK^T) ----------------
__global__ __launch_bounds__(512, 4) void attn_fwd(const unsigned short* __restrict__ Q,
                                                   const unsigned short* __restrict__ Kt,
                                                   const unsigned short* __restrict__ VT,
                                                   unsigned short* __restrict__ O) {
  __shared__ alignas(16) unsigned short lds[2][16384];   // 64 KB
  __shared__ alignas(16) unsigned short plds[8][1024];   // 16 KB, per-wave P [16 q][64 kv]
  const int t = threadIdx.x;
  const int wid = t >> 6, lane = t & 63;
  const int llo = lane & 15, lhi = lane >> 4;
  const int j0 = blockIdx.x;
  int bh, g;
  if (j0 < 256) { bh = j0 & 31; g = 15 - (j0 >> 5); }
  else          { bh = (j0 - 256) & 31; g = (j0 - 256) >> 5; }
  const int qbase = g * 128;
  const int nt = 2 * g + 2;
  const size_t bh_td = (size_t)bh * SEQ * HD;
  const size_t bh_dt = (size_t)bh * HD * SEQ;
  unsigned short* pw = &plds[wid][0];
  const int fvl = (llo & 7) ^ ((llo & 8) >> 1);
  const int pkey = llo & 14;

  auto stage = [&](int buf, int j) {
    const int t0 = j * 64;
    #pragma unroll
    for (int i = 0; i < 2; ++i) {
      const int c = i * 512 + t;
      const int row = c >> 4, slot = c & 15;
      gload_lds16(Kt + bh_td + (size_t)(t0 + row) * HD + ((slot ^ (row & 15)) << 3),
                  &lds[buf][(size_t)(i * 512 + wid * 64) * 8]);
    }
    #pragma unroll
    for (int i = 0; i < 2; ++i) {
      const int c = i * 512 + t;
      const int vrow = c >> 3, vslot = c & 7;
      const int fv = (vrow & 7) ^ ((vrow & 8) >> 1);
      gload_lds16(VT + bh_dt + (size_t)vrow * SEQ + t0 + ((vslot ^ fv) << 3),
                  &lds[buf][8192 + (size_t)(i * 512 + wid * 64) * 8]);
    }
  };

  bf16x8 qa[4];
  {
    const unsigned short* qp = Q + bh_td + (size_t)(qbase + wid * 16 + llo) * HD + lhi * 8;
    #pragma unroll
    for (int kk = 0; kk < 4; ++kk) qa[kk] = *(const bf16x8*)(qp + kk * 32);
  }
  f32x4 oacc[8] = {};
  float m_r = -1e30f, l_r = 0.f;

  stage(0, 0);
  for (int j = 0; j < nt; ++j) {
    const int cur = j & 1;
    __syncthreads();
    if (j + 1 < nt) stage(cur ^ 1, j + 1);
    f32x4 s[4] = {};
    __builtin_amdgcn_s_setprio(1);
    #pragma unroll
    for (int nb = 0; nb < 4; ++nb) {
      const int row = nb * 16 + llo;
      #pragma unroll
      for (int kk = 0; kk < 4; ++kk) {
        const bf16x8 kb = *(const bf16x8*)&lds[cur][row * 128 + (((kk * 4 + lhi) ^ llo) << 3)];
        s[nb] = __builtin_amdgcn_mfma_f32_16x16x32_bf16(kb, qa[kk], s[nb], 0, 0, 0);
      }
    }
    __builtin_amdgcn_s_setprio(0);
    if (j >= nt - 2) {
      const int q = qbase + wid * 16 + llo;
      #pragma unroll
      for (int nb = 0; nb < 4; ++nb)
        #pragma unroll
        for (int r = 0; r < 4; ++r)
          if (j * 64 + nb * 16 + lhi * 4 + r > q) s[nb][r] = -1e30f;
    }
    float mloc = -1e30f;
    #pragma unroll
    for (int nb = 0; nb < 4; ++nb)
      #pragma unroll
      for (int r = 0; r < 4; ++r) mloc = fmaxf(mloc, s[nb][r]);
    mloc = fmaxf(mloc, __shfl_xor(mloc, 16));
    mloc = fmaxf(mloc, __shfl_xor(mloc, 32));
    float alq = 1.f;
    if (__any(mloc > m_r + 8.f)) {
      const float mn = fmaxf(m_r, mloc);
      alq = __expf(m_r - mn);
      m_r = mn;
      float alr[4];
      #pragma unroll
      for (int r = 0; r < 4; ++r) alr[r] = __shfl(alq, lhi * 4 + r);
      #pragma unroll
      for (int db = 0; db < 8; ++db)
        #pragma unroll
        for (int r = 0; r < 4; ++r) oacc[db][r] *= alr[r];
    }
    float ps = 0.f;
    #pragma unroll
    for (int nb = 0; nb < 4; ++nb) {
      const float p0 = __expf(s[nb][0] - m_r), p1 = __expf(s[nb][1] - m_r);
      const float p2 = __expf(s[nb][2] - m_r), p3 = __expf(s[nb][3] - m_r);
      ps += (p0 + p1) + (p2 + p3);
      uint2 uu;
      uu.x = (uint32_t)f2bf(p0) | ((uint32_t)f2bf(p1) << 16);
      uu.y = (uint32_t)f2bf(p2) | ((uint32_t)f2bf(p3) << 16);
      *(uint2*)&pw[llo * 64 + (((nb * 4 + lhi) ^ pkey) << 2)] = uu;
    }
    ps += __shfl_xor(ps, 16);
    ps += __shfl_xor(ps, 32);
    l_r = l_r * alq + ps;
    asm volatile("s_waitcnt lgkmcnt(0)" ::: "memory");
    __builtin_amdgcn_sched_barrier(0);
    const bf16x8 pa0 = *(const bf16x8*)&pw[llo * 64 + (((lhi * 2) ^ pkey) << 2)];
    const bf16x8 pa1 = *(const bf16x8*)&pw[llo * 64 + (((8 + lhi * 2) ^ pkey) << 2)];
    __builtin_amdgcn_s_setprio(1);
    #pragma unroll
    for (int db = 0; db < 8; ++db) {
      const unsigned short* vbp = &lds[cur][8192 + (db * 16 + llo) * 64];
      const bf16x8 vb0 = *(const bf16x8*)&vbp[(lhi ^ fvl) << 3];
      const bf16x8 vb1 = *(const bf16x8*)&vbp[((4 + lhi) ^ fvl) << 3];
      oacc[db] = __builtin_amdgcn_mfma_f32_16x16x32_bf16(pa0, vb0, oacc[db], 0, 0, 0);
      oacc[db] = __builtin_amdgcn_mfma_f32_16x16x32_bf16(pa1, vb1, oacc[db], 0, 0, 0);
    }
    __builtin_amdgcn_s_setprio(0);
  }

  const int b = bh >> 4, h = bh & 15;
  const float invq = 1.f / l_r;
  float invr[4];
  #pragma unroll
  for (int r = 0; r < 4; ++r) invr[r] = __shfl(invq, lhi * 4 + r);
  #pragma unroll
  for (int db = 0; db < 8; ++db)
    #pragma unroll
    for (int r = 0; r < 4; ++r) {
      const int qi = qbase + wid * 16 + lhi * 4 + r;
      const int d = db * 16 + llo;
      O[((size_t)(b * SEQ + qi)) * D_MODEL + h * HD + d] = f2bf(oacc[db][r] * invr[r]);
    }
}

extern "C" void kernel_launch(void* const* d_in, const int* in_sizes, int n_in,
                              void* d_out, int out_size, void* d_ws, size_t ws_size,
                              hipStream_t stream) {
  const float* x  = (const float*)d_in[0];
  const float* wq = (const float*)d_in[1];
  const float* wk = (const float*)d_in[2];
  const float* wv = (const float*)d_in[3];
  const float* wo = (const float*)d_in[4];

  char* ws = (char*)d_ws;
  float* scales   = (float*)ws;                     // 4 f32
  float* partials = (float*)(ws + 256);             // 4*4096 f32
  unsigned short* xbf   = (unsigned short*)(ws + 131072);
  const size_t nMD = (size_t)M_TOT * D_MODEL;
  unsigned short* signs = xbf + nMD;
  unsigned short* Qb = signs + 4 * (size_t)NELEM_W;
  unsigned short* Kb = Qb + nMD;
  unsigned short* Vt = Kb + nMD;
  unsigned short* Ab = Vt + nMD;

  sign_w<<<dim3(4096, 4), 256, 0, stream>>>(wq, wk, wv, wo, signs, partials);
  reduce2<<<dim3(4), 256, 0, stream>>>(partials, scales);
  cvt_x<<<dim3(8192), 256, 0, stream>>>(x, xbf);

  // fused QKV: N = 6144 (wq|wk|wv signs are contiguous), grid 16x48 = 768 blocks
  gemm_p<0><<<dim3(768), 512, 0, stream>>>(xbf, signs, Qb, Kb, Vt, nullptr, scales);

  attn_fwd<<<dim3(512), 512, 0, stream>>>(Qb, Kb, Vt, Ab);

  // output projection: f32 out, grid 16x16 = 256 blocks
  gemm_p<1><<<dim3(256), 512, 0, stream>>>(Ab, signs + 3 * (size_t)NELEM_W,
                                           nullptr, nullptr, nullptr, (float*)d_out, scales);
}

// Round 6
// 263.674 us; speedup vs baseline: 1.0514x; 1.0514x over previous
//
#include <hip/hip_runtime.h>
#include <stdint.h>

#define D_MODEL 2048
#define SEQ     2048
#define BATCH   2
#define NH      16
#define HD      128
#define M_TOT   (BATCH*SEQ)          // 4096
#define NELEM_W (D_MODEL*D_MODEL)    // 4194304

typedef float f32x4 __attribute__((ext_vector_type(4)));
typedef short bf16x8 __attribute__((ext_vector_type(8)));

__device__ __forceinline__ unsigned short f2bf(float f) {
  union { float f; uint32_t u; } v; v.f = f;
  uint32_t r = v.u + 0x7FFFu + ((v.u >> 16) & 1u);
  return (unsigned short)(r >> 16);
}

__device__ __forceinline__ void gload_lds16(const unsigned short* g, unsigned short* l) {
  __builtin_amdgcn_global_load_lds(
      (const __attribute__((address_space(1))) unsigned int*)g,
      (__attribute__((address_space(3))) unsigned int*)l, 16, 0, 0);
}

// ---------------- sign(w) as bf16 ±1, fused |w| partial reduction ----------------
__global__ __launch_bounds__(256) void sign_w(const float* w0, const float* w1,
                                              const float* w2, const float* w3,
                                              unsigned short* signs, float* partials) {
  const int wi = blockIdx.y;
  const float* w = (wi == 0) ? w0 : (wi == 1) ? w1 : (wi == 2) ? w2 : w3;
  unsigned short* o = signs + (size_t)wi * NELEM_W;
  const int t = threadIdx.x;
  const int i = blockIdx.x * 256 + t;
  float4 v = ((const float4*)w)[i];
  ushort4 s;
  s.x = (v.x > 0.f) ? 0x3F80u : ((v.x < 0.f) ? 0xBF80u : 0u);
  s.y = (v.y > 0.f) ? 0x3F80u : ((v.y < 0.f) ? 0xBF80u : 0u);
  s.z = (v.z > 0.f) ? 0x3F80u : ((v.z < 0.f) ? 0xBF80u : 0u);
  s.w = (v.w > 0.f) ? 0x3F80u : ((v.w < 0.f) ? 0xBF80u : 0u);
  ((ushort4*)o)[i] = s;
  float a = fabsf(v.x) + fabsf(v.y) + fabsf(v.z) + fabsf(v.w);
  #pragma unroll
  for (int off = 32; off; off >>= 1) a += __shfl_down(a, off);
  __shared__ float sm[4];
  if ((t & 63) == 0) sm[t >> 6] = a;
  __syncthreads();
  if (t == 0) partials[wi * 4096 + blockIdx.x] = sm[0] + sm[1] + sm[2] + sm[3];
}

__global__ __launch_bounds__(256) void reduce2(const float* partials, float* scales) {
  const int wi = blockIdx.x, t = threadIdx.x;
  float s = 0.f;
  #pragma unroll
  for (int i = 0; i < 16; ++i) s += partials[wi * 4096 + i * 256 + t];
  #pragma unroll
  for (int off = 32; off; off >>= 1) s += __shfl_down(s, off);
  __shared__ float sm[4];
  if ((t & 63) == 0) sm[t >> 6] = s;
  __syncthreads();
  if (t == 0) scales[wi] = fmaxf((sm[0] + sm[1] + sm[2] + sm[3]) * (1.f / 4194304.f), 1e-5f);
}

// ---------------- x -> bf16 ----------------
__global__ __launch_bounds__(256) void cvt_x(const float* x, unsigned short* xb) {
  const int i = blockIdx.x * 256 + threadIdx.x;
  float4 v = ((const float4*)x)[i];
  ushort4 o;
  o.x = f2bf(v.x); o.y = f2bf(v.y); o.z = f2bf(v.z); o.w = f2bf(v.w);
  ((ushort4*)xb)[i] = o;
}

// ---------------- pipelined GEMM: C[4096][N] = A[M][2048] * W[col][2048]^T ----------
// BM=256, BN=128, BK=64, 8 waves (4M x 2N, per-wave 64x64).
// 3-buffer LDS (144 KB), lead-2 tile staging, ONE counted vmcnt + ONE raw barrier
// per K-tile. Tile body (stages + 16 ds_reads + 32 MFMA) is compiler-scheduled.
// MODE 0: fused QKV (W = signs base, 3 regions of 2048 cols -> Qb/Kb layout or Vt^T)
// MODE 1: f32 out row-major (WO)
template <int MODE>
__global__ __launch_bounds__(512, 2) void gemm_p(const unsigned short* __restrict__ A,
                                                 const unsigned short* __restrict__ W,
                                                 unsigned short* __restrict__ Qb,
                                                 unsigned short* __restrict__ Kb,
                                                 unsigned short* __restrict__ Vt,
                                                 float* __restrict__ outf,
                                                 const float* __restrict__ scales) {
  constexpr int K = 2048;
  constexpr int NT = 32;               // K-tiles
  constexpr int BUF = 24576;           // elems per buffer: A 256x64 (32KB) + B 128x64 (16KB)
  __shared__ alignas(16) unsigned short lds[3 * BUF];   // 144 KB
  const int t = threadIdx.x;
  const int wid = t >> 6, lane = t & 63;
  const int llo = lane & 15, lhi = lane >> 4;
  const int wm = wid >> 2, wn = wid & 3;   // placeholder (overwritten below)
  (void)wm; (void)wn;
  const int wmr = wid >> 1, wnr = wid & 1; // 4M x 2N

  // XCD-aware swizzle (grid % 8 == 0), m-fast within XCD chunk (shares B panel)
  const int nwg = gridDim.x;
  const int bid = blockIdx.x;
  const int sid = (bid & 7) * (nwg >> 3) + (bid >> 3);
  const int mt = sid & 15, nt_ = sid >> 4;
  const int m0 = mt * 256;
  const int n0w = nt_ * 128;            // global weight-row (output col) base

  auto stageA = [&](int buf, int kt) {
    const int k0 = kt * 64;
    #pragma unroll
    for (int i = 0; i < 4; ++i) {
      const int c = i * 512 + t;
      const int row = c >> 3, slot = c & 7;
      gload_lds16(A + (size_t)(m0 + row) * K + k0 + ((slot ^ (row & 7)) << 3),
                  &lds[buf * BUF + (i * 512 + wid * 64) * 8]);
    }
  };
  auto stageB = [&](int buf, int kt) {
    const int k0 = kt * 64;
    #pragma unroll
    for (int i = 0; i < 2; ++i) {
      const int c = i * 512 + t;
      const int row = c >> 3, slot = c & 7;
      gload_lds16(W + (size_t)(n0w + row) * K + k0 + ((slot ^ (row & 7)) << 3),
                  &lds[buf * BUF + 16384 + (i * 512 + wid * 64) * 8]);
    }
  };

  f32x4 acc[4][4] = {};

  // prologue: tiles 0,1 staged; wait tile 0 (oldest 6 of 12 loads)
  stageA(0, 0); stageB(0, 0);
  stageA(1, 1); stageB(1, 1);
  asm volatile("s_waitcnt vmcnt(6)" ::: "memory");
  __builtin_amdgcn_s_barrier();

  for (int kt = 0; kt < NT; ++kt) {
    const int cur = kt % 3;
    const int nb3 = (kt + 2) % 3;
    const bool pf = (kt + 2) < NT;
    // stage tile kt+2 (6 global->LDS loads, in flight across barriers)
    if (pf) { stageA(nb3, kt + 2); stageB(nb3, kt + 2); }
    // register fragments (plain loads; compiler schedules lgkmcnt/MFMA interleave)
    bf16x8 a[4][2], b[4][2];
    #pragma unroll
    for (int f = 0; f < 4; ++f) {
      const int ra = wmr * 64 + f * 16 + llo;
      #pragma unroll
      for (int kk = 0; kk < 2; ++kk)
        a[f][kk] = *(const bf16x8*)&lds[cur * BUF + ra * 64 + (((kk * 4 + lhi) ^ (ra & 7)) << 3)];
    }
    #pragma unroll
    for (int f = 0; f < 4; ++f) {
      const int rb = wnr * 64 + f * 16 + llo;
      #pragma unroll
      for (int kk = 0; kk < 2; ++kk)
        b[f][kk] = *(const bf16x8*)&lds[cur * BUF + 16384 + rb * 64 + (((kk * 4 + lhi) ^ (rb & 7)) << 3)];
    }
    __builtin_amdgcn_s_setprio(1);
    #pragma unroll
    for (int kk = 0; kk < 2; ++kk)
      #pragma unroll
      for (int fm = 0; fm < 4; ++fm)
        #pragma unroll
        for (int fn = 0; fn < 4; ++fn)
          acc[fm][fn] = __builtin_amdgcn_mfma_f32_16x16x32_bf16(a[fm][kk], b[fn][kk], acc[fm][fn], 0, 0, 0);
    __builtin_amdgcn_s_setprio(0);
    // tile boundary: counted vmcnt (tile kt+1 landed; kt+2's 6 loads stay in flight)
    if (kt < NT - 1) {
      if (kt <= NT - 3) asm volatile("s_waitcnt vmcnt(6)" ::: "memory");
      else              asm volatile("s_waitcnt vmcnt(0)" ::: "memory");
      __builtin_amdgcn_s_barrier();
    }
  }

  // ---- epilogue ----
  if (MODE == 1) {
    const float sc = scales[3];
    #pragma unroll
    for (int fm = 0; fm < 4; ++fm)
      #pragma unroll
      for (int fn = 0; fn < 4; ++fn)
        #pragma unroll
        for (int r = 0; r < 4; ++r) {
          const int row = m0 + wmr * 64 + fm * 16 + lhi * 4 + r;
          const int col = n0w + wnr * 64 + fn * 16 + llo;
          outf[(size_t)row * D_MODEL + col] = acc[fm][fn][r] * sc;
        }
  } else {
    const int region = n0w >> 11;                 // 0=Q 1=K 2=V
    const int c0 = (n0w & 2047) + wnr * 64;       // col base within region
    const float sc = scales[region] * (region == 0 ? 0.08838834764831845f : 1.f);
    unsigned short* outb = (region == 0) ? Qb : (region == 1) ? Kb : Vt;
    #pragma unroll
    for (int fm = 0; fm < 4; ++fm)
      #pragma unroll
      for (int fn = 0; fn < 4; ++fn)
        #pragma unroll
        for (int r = 0; r < 4; ++r) {
          const int row = m0 + wmr * 64 + fm * 16 + lhi * 4 + r;
          const int colr = c0 + fn * 16 + llo;
          const int b_ = row >> 11, tt = row & 2047, h = colr >> 7, d = colr & 127;
          size_t idx;
          if (region < 2) idx = ((size_t)((b_ * NH + h) * SEQ + tt)) * HD + d;
          else            idx = ((size_t)((b_ * NH + h) * HD + d)) * SEQ + tt;
          outb[idx] = f2bf(acc[fm][fn][r] * sc);
        }
  }
}

// ---------------- causal flash attention (8-wave, QBLK=128, swapped QK^T) ----------------
__global__ __launch_bounds__(512, 4) void attn_fwd(const unsigned short* __restrict__ Q,
                                                   const unsigned short* __restrict__ Kt,
                                                   const unsigned short* __restrict__ VT,
                                                   unsigned short* __restrict__ O) {
  __shared__ alignas(16) unsigned short lds[2][16384];   // 64 KB
  __shared__ alignas(16) unsigned short plds[8][1024];   // 16 KB, per-wave P [16 q][64 kv]
  const int t = threadIdx.x;
  const int wid = t >> 6, lane = t & 63;
  const int llo = lane & 15, lhi = lane >> 4;
  const int j0 = blockIdx.x;
  int bh, g;
  if (j0 < 256) { bh = j0 & 31; g = 15 - (j0 >> 5); }
  else          { bh = (j0 - 256) & 31; g = (j0 - 256) >> 5; }
  const int qbase = g * 128;
  const int nt = 2 * g + 2;
  const size_t bh_td = (size_t)bh * SEQ * HD;
  const size_t bh_dt = (size_t)bh * HD * SEQ;
  unsigned short* pw = &plds[wid][0];
  const int fvl = (llo & 7) ^ ((llo & 8) >> 1);
  const int pkey = llo & 14;

  auto stage = [&](int buf, int j) {
    const int t0 = j * 64;
    #pragma unroll
    for (int i = 0; i < 2; ++i) {
      const int c = i * 512 + t;
      const int row = c >> 4, slot = c & 15;
      gload_lds16(Kt + bh_td + (size_t)(t0 + row) * HD + ((slot ^ (row & 15)) << 3),
                  &lds[buf][(size_t)(i * 512 + wid * 64) * 8]);
    }
    #pragma unroll
    for (int i = 0; i < 2; ++i) {
      const int c = i * 512 + t;
      const int vrow = c >> 3, vslot = c & 7;
      const int fv = (vrow & 7) ^ ((vrow & 8) >> 1);
      gload_lds16(VT + bh_dt + (size_t)vrow * SEQ + t0 + ((vslot ^ fv) << 3),
                  &lds[buf][8192 + (size_t)(i * 512 + wid * 64) * 8]);
    }
  };

  bf16x8 qa[4];
  {
    const unsigned short* qp = Q + bh_td + (size_t)(qbase + wid * 16 + llo) * HD + lhi * 8;
    #pragma unroll
    for (int kk = 0; kk < 4; ++kk) qa[kk] = *(const bf16x8*)(qp + kk * 32);
  }
  f32x4 oacc[8] = {};
  float m_r = -1e30f, l_r = 0.f;

  stage(0, 0);
  for (int j = 0; j < nt; ++j) {
    const int cur = j & 1;
    __syncthreads();
    if (j + 1 < nt) stage(cur ^ 1, j + 1);
    f32x4 s[4] = {};
    __builtin_amdgcn_s_setprio(1);
    #pragma unroll
    for (int nb = 0; nb < 4; ++nb) {
      const int row = nb * 16 + llo;
      #pragma unroll
      for (int kk = 0; kk < 4; ++kk) {
        const bf16x8 kb = *(const bf16x8*)&lds[cur][row * 128 + (((kk * 4 + lhi) ^ llo) << 3)];
        s[nb] = __builtin_amdgcn_mfma_f32_16x16x32_bf16(kb, qa[kk], s[nb], 0, 0, 0);
      }
    }
    __builtin_amdgcn_s_setprio(0);
    if (j >= nt - 2) {
      const int q = qbase + wid * 16 + llo;
      #pragma unroll
      for (int nb = 0; nb < 4; ++nb)
        #pragma unroll
        for (int r = 0; r < 4; ++r)
          if (j * 64 + nb * 16 + lhi * 4 + r > q) s[nb][r] = -1e30f;
    }
    float mloc = -1e30f;
    #pragma unroll
    for (int nb = 0; nb < 4; ++nb)
      #pragma unroll
      for (int r = 0; r < 4; ++r) mloc = fmaxf(mloc, s[nb][r]);
    mloc = fmaxf(mloc, __shfl_xor(mloc, 16));
    mloc = fmaxf(mloc, __shfl_xor(mloc, 32));
    float alq = 1.f;
    if (__any(mloc > m_r + 8.f)) {
      const float mn = fmaxf(m_r, mloc);
      alq = __expf(m_r - mn);
      m_r = mn;
      float alr[4];
      #pragma unroll
      for (int r = 0; r < 4; ++r) alr[r] = __shfl(alq, lhi * 4 + r);
      #pragma unroll
      for (int db = 0; db < 8; ++db)
        #pragma unroll
        for (int r = 0; r < 4; ++r) oacc[db][r] *= alr[r];
    }
    float ps = 0.f;
    #pragma unroll
    for (int nb = 0; nb < 4; ++nb) {
      const float p0 = __expf(s[nb][0] - m_r), p1 = __expf(s[nb][1] - m_r);
      const float p2 = __expf(s[nb][2] - m_r), p3 = __expf(s[nb][3] - m_r);
      ps += (p0 + p1) + (p2 + p3);
      uint2 uu;
      uu.x = (uint32_t)f2bf(p0) | ((uint32_t)f2bf(p1) << 16);
      uu.y = (uint32_t)f2bf(p2) | ((uint32_t)f2bf(p3) << 16);
      *(uint2*)&pw[llo * 64 + (((nb * 4 + lhi) ^ pkey) << 2)] = uu;
    }
    ps += __shfl_xor(ps, 16);
    ps += __shfl_xor(ps, 32);
    l_r = l_r * alq + ps;
    asm volatile("s_waitcnt lgkmcnt(0)" ::: "memory");
    __builtin_amdgcn_sched_barrier(0);
    const bf16x8 pa0 = *(const bf16x8*)&pw[llo * 64 + (((lhi * 2) ^ pkey) << 2)];
    const bf16x8 pa1 = *(const bf16x8*)&pw[llo * 64 + (((8 + lhi * 2) ^ pkey) << 2)];
    __builtin_amdgcn_s_setprio(1);
    #pragma unroll
    for (int db = 0; db < 8; ++db) {
      const unsigned short* vbp = &lds[cur][8192 + (db * 16 + llo) * 64];
      const bf16x8 vb0 = *(const bf16x8*)&vbp[(lhi ^ fvl) << 3];
      const bf16x8 vb1 = *(const bf16x8*)&vbp[((4 + lhi) ^ fvl) << 3];
      oacc[db] = __builtin_amdgcn_mfma_f32_16x16x32_bf16(pa0, vb0, oacc[db], 0, 0, 0);
      oacc[db] = __builtin_amdgcn_mfma_f32_16x16x32_bf16(pa1, vb1, oacc[db], 0, 0, 0);
    }
    __builtin_amdgcn_s_setprio(0);
  }

  const int b = bh >> 4, h = bh & 15;
  const float invq = 1.f / l_r;
  float invr[4];
  #pragma unroll
  for (int r = 0; r < 4; ++r) invr[r] = __shfl(invq, lhi * 4 + r);
  #pragma unroll
  for (int db = 0; db < 8; ++db)
    #pragma unroll
    for (int r = 0; r < 4; ++r) {
      const int qi = qbase + wid * 16 + lhi * 4 + r;
      const int d = db * 16 + llo;
      O[((size_t)(b * SEQ + qi)) * D_MODEL + h * HD + d] = f2bf(oacc[db][r] * invr[r]);
    }
}

extern "C" void kernel_launch(void* const* d_in, const int* in_sizes, int n_in,
                              void* d_out, int out_size, void* d_ws, size_t ws_size,
                              hipStream_t stream) {
  const float* x  = (const float*)d_in[0];
  const float* wq = (const float*)d_in[1];
  const float* wk = (const float*)d_in[2];
  const float* wv = (const float*)d_in[3];
  const float* wo = (const float*)d_in[4];

  char* ws = (char*)d_ws;
  float* scales   = (float*)ws;                     // 4 f32
  float* partials = (float*)(ws + 256);             // 4*4096 f32
  unsigned short* xbf   = (unsigned short*)(ws + 131072);
  const size_t nMD = (size_t)M_TOT * D_MODEL;
  unsigned short* signs = xbf + nMD;
  unsigned short* Qb = signs + 4 * (size_t)NELEM_W;
  unsigned short* Kb = Qb + nMD;
  unsigned short* Vt = Kb + nMD;
  unsigned short* Ab = Vt + nMD;

  sign_w<<<dim3(4096, 4), 256, 0, stream>>>(wq, wk, wv, wo, signs, partials);
  reduce2<<<dim3(4), 256, 0, stream>>>(partials, scales);
  cvt_x<<<dim3(8192), 256, 0, stream>>>(x, xbf);

  // fused QKV: N = 6144 (wq|wk|wv signs contiguous), grid 768 = 3 blocks/CU exactly
  gemm_p<0><<<dim3(768), 512, 0, stream>>>(xbf, signs, Qb, Kb, Vt, nullptr, scales);

  attn_fwd<<<dim3(512), 512, 0, stream>>>(Qb, Kb, Vt, Ab);

  // output projection: f32 out, grid 256 = 1 block/CU exactly
  gemm_p<1><<<dim3(256), 512, 0, stream>>>(Ab, signs + 3 * (size_t)NELEM_W,
                                           nullptr, nullptr, nullptr, (float*)d_out, scales);
}